// Round 1
// baseline (21.445 us; speedup 1.0000x reference)
//
#include <hip/hip_runtime.h>

// MedSAM3D neighborhood compression:
//   out[f,h,w] = sum_n img[f,h,w,n] * W[f,n]
// B=1, F=256, H=W=64, N=25. Pure memory-bound (109 MB traffic, 52 MFLOP).
//
// Strategy: block = 256 threads = 256 contiguous outputs (within ONE channel
// f, since 256 | 64*64). Stage the 25,600 B input chunk to LDS via coalesced
// float4 loads; each thread then dots its 25-float LDS row (stride 25 = odd
// -> 2 lanes/bank = conflict-free) against the block-uniform W[f,:] (compiles
// to scalar loads).

constexpr int N_NEIGH = 25;
constexpr int BLOCK   = 256;
constexpr int CHUNK_F4 = BLOCK * N_NEIGH / 4;  // 1600 float4 per block

__global__ __launch_bounds__(BLOCK) void medsam_compress_kernel(
    const float* __restrict__ img,   // [F*H*W*N] contiguous
    const float* __restrict__ W,     // [F*N]
    float* __restrict__ out)         // [F*H*W]
{
    __shared__ float lds[BLOCK * N_NEIGH];  // 25,600 B

    const int bid = blockIdx.x;
    const int tid = threadIdx.x;

    // ---- stage input chunk: 1600 float4, fully coalesced ----
    const float4* __restrict__ src4 =
        reinterpret_cast<const float4*>(img + (long long)bid * (BLOCK * N_NEIGH));
    float4* dst4 = reinterpret_cast<float4*>(lds);
    #pragma unroll
    for (int k = 0; k < 6; ++k)
        dst4[tid + k * BLOCK] = src4[tid + k * BLOCK];
    if (tid < CHUNK_F4 - 6 * BLOCK)  // 64 leftover float4
        dst4[tid + 6 * BLOCK] = src4[tid + 6 * BLOCK];

    // ---- W row for this block's channel (block-uniform -> s_load) ----
    const int f = bid >> 4;  // 4096 outputs per channel / 256 per block = 16
    const float* __restrict__ Wf = W + f * N_NEIGH;
    float w[N_NEIGH];
    #pragma unroll
    for (int n = 0; n < N_NEIGH; ++n) w[n] = Wf[n];

    __syncthreads();

    // ---- dot: 25 ds_read_b32 at lane-stride 25 (odd -> conflict-free) ----
    const float* row = lds + tid * N_NEIGH;
    float acc = 0.f;
    #pragma unroll
    for (int n = 0; n < N_NEIGH; ++n)
        acc += row[n] * w[n];

    out[(long long)bid * BLOCK + tid] = acc;
}

extern "C" void kernel_launch(void* const* d_in, const int* in_sizes, int n_in,
                              void* d_out, int out_size, void* d_ws, size_t ws_size,
                              hipStream_t stream) {
    const float* img = (const float*)d_in[0];  // (1,256,64,64,25) f32
    const float* W   = (const float*)d_in[1];  // (256,25) f32
    float* out       = (float*)d_out;          // (1,256,64,64) f32

    const int total_out = out_size;            // 1,048,576
    const int grid = total_out / BLOCK;        // 4096 blocks

    medsam_compress_kernel<<<grid, BLOCK, 0, stream>>>(img, W, out);
}